// Round 1
// baseline (261.586 us; speedup 1.0000x reference)
//
#include <hip/hip_runtime.h>

#define NUM_LAYERS 1000
#define DIM 10
#define CHUNKS 32
#define CH 32            // ceil(1000/32) -> chunks 0..30 full, chunk 31 has 8 layers
#define AFF_STRIDE 128   // floats per stored chunk affine (10x11 = 110, padded)

// ---------------------------------------------------------------------------
// Kernel A: each block composes layers [c*CH, min(L,(c+1)*CH)) into one
// augmented affine [M | c] (10 rows x 11 cols). Lane j (0..10) owns column j
// in registers; weight values are wave-uniform -> scalar loads (broadcast).
// ---------------------------------------------------------------------------
__global__ void compose_chunks(const float* __restrict__ Ws,
                               const float* __restrict__ bs,
                               float* __restrict__ ws) {
    const int chunk = blockIdx.x;
    const int lane  = threadIdx.x;
    if (lane > DIM) return;                 // lanes 0..9 = M columns, lane 10 = bias col
    const bool isBias = (lane == DIM);

    const int l0 = chunk * CH;
    const int l1 = min(NUM_LAYERS, l0 + CH);

    float col[DIM];
    // init with first layer's affine: M = W_{l0}, c = b_{l0}
    {
        const float* W = Ws + (size_t)l0 * DIM * DIM;
        if (isBias) {
            #pragma unroll
            for (int r = 0; r < DIM; ++r) col[r] = bs[l0 * DIM + r];
        } else {
            #pragma unroll
            for (int r = 0; r < DIM; ++r) col[r] = W[r * DIM + lane];
        }
    }

    for (int l = l0 + 1; l < l1; ++l) {
        const float* Wl = Ws + (size_t)l * DIM * DIM;   // uniform address -> s_load
        float ncol[DIM];
        #pragma unroll
        for (int r = 0; r < DIM; ++r) {
            float acc = 0.f;
            #pragma unroll
            for (int k = 0; k < DIM; ++k)
                acc += Wl[r * DIM + k] * col[k];
            ncol[r] = acc;
        }
        #pragma unroll
        for (int r = 0; r < DIM; ++r) col[r] = ncol[r];
        if (isBias) {
            #pragma unroll
            for (int r = 0; r < DIM; ++r) col[r] += bs[l * DIM + r];
        }
    }

    // store column-major: ws[chunk*AFF_STRIDE + col*10 + r]
    float* o = ws + chunk * AFF_STRIDE + lane * DIM;
    #pragma unroll
    for (int r = 0; r < DIM; ++r) o[r] = col[r];
}

// ---------------------------------------------------------------------------
// Kernel B: one wave folds the CHUNKS chunk-affines (in order) into the final
// affine. Same column-ownership trick; M_i values are uniform -> s_load.
// Output layout: aff[r*10 + j] = M[r][j] (row-major), aff[100 + r] = c[r].
// ---------------------------------------------------------------------------
__global__ void compose_final(const float* __restrict__ ws_in,
                              float* __restrict__ aff) {
    const int lane = threadIdx.x;
    if (lane > DIM) return;
    const bool isBias = (lane == DIM);

    float col[DIM];
    #pragma unroll
    for (int r = 0; r < DIM; ++r) col[r] = ws_in[lane * DIM + r];  // chunk 0

    for (int i = 1; i < CHUNKS; ++i) {
        const float* Mi = ws_in + i * AFF_STRIDE;   // col-major: M_i[r][k] at k*10+r
        float ncol[DIM];
        #pragma unroll
        for (int r = 0; r < DIM; ++r) {
            float acc = 0.f;
            #pragma unroll
            for (int k = 0; k < DIM; ++k)
                acc += Mi[k * DIM + r] * col[k];
            ncol[r] = acc;
        }
        #pragma unroll
        for (int r = 0; r < DIM; ++r) col[r] = ncol[r];
        if (isBias) {
            #pragma unroll
            for (int r = 0; r < DIM; ++r) col[r] += Mi[DIM * DIM + r];
        }
    }

    if (isBias) {
        #pragma unroll
        for (int r = 0; r < DIM; ++r) aff[DIM * DIM + r] = col[r];
    } else {
        #pragma unroll
        for (int r = 0; r < DIM; ++r) aff[r * DIM + lane] = col[r];
    }
}

// ---------------------------------------------------------------------------
// Kernel C: apply out = M x + c. Two rows per thread -> 80 B = 5 x float4,
// 16B-aligned fully-coalesced loads/stores. Affine broadcast from LDS
// (uniform address per instruction -> hardware broadcast, no bank conflicts).
// ---------------------------------------------------------------------------
__global__ __launch_bounds__(256) void apply_affine(const float* __restrict__ x,
                                                    const float* __restrict__ aff,
                                                    float* __restrict__ out,
                                                    int npairs) {
    __shared__ float s[112];
    if (threadIdx.x < 112)
        s[threadIdx.x] = (threadIdx.x < 110) ? aff[threadIdx.x] : 0.f;
    __syncthreads();

    const int t = blockIdx.x * blockDim.x + threadIdx.x;
    if (t >= npairs) return;

    const float4* xin = (const float4*)x + (size_t)t * 5;
    float4 v0 = xin[0], v1 = xin[1], v2 = xin[2], v3 = xin[3], v4 = xin[4];
    float xv[20] = {v0.x, v0.y, v0.z, v0.w,  v1.x, v1.y, v1.z, v1.w,
                    v2.x, v2.y, v2.z, v2.w,  v3.x, v3.y, v3.z, v3.w,
                    v4.x, v4.y, v4.z, v4.w};
    float o[20];
    #pragma unroll
    for (int rr = 0; rr < 2; ++rr) {
        #pragma unroll
        for (int j = 0; j < DIM; ++j) {
            float acc = s[100 + j];
            #pragma unroll
            for (int k = 0; k < DIM; ++k)
                acc += s[j * DIM + k] * xv[rr * DIM + k];
            o[rr * DIM + j] = acc;
        }
    }

    float4* op = (float4*)out + (size_t)t * 5;
    op[0] = make_float4(o[0],  o[1],  o[2],  o[3]);
    op[1] = make_float4(o[4],  o[5],  o[6],  o[7]);
    op[2] = make_float4(o[8],  o[9],  o[10], o[11]);
    op[3] = make_float4(o[12], o[13], o[14], o[15]);
    op[4] = make_float4(o[16], o[17], o[18], o[19]);
}

extern "C" void kernel_launch(void* const* d_in, const int* in_sizes, int n_in,
                              void* d_out, int out_size, void* d_ws, size_t ws_size,
                              hipStream_t stream) {
    const float* x  = (const float*)d_in[0];   // [BATCH, 10]
    const float* Ws = (const float*)d_in[1];   // [1000, 10, 10]
    const float* bs = (const float*)d_in[2];   // [1000, 10]
    float* out = (float*)d_out;

    float* ws_chunks = (float*)d_ws;                       // CHUNKS * AFF_STRIDE floats
    float* ws_aff    = ws_chunks + CHUNKS * AFF_STRIDE;    // 110 floats (final affine)

    const int batch  = in_sizes[0] / DIM;      // 2,000,000
    const int npairs = batch / 2;              // 1,000,000 (batch is even)

    compose_chunks<<<CHUNKS, 64, 0, stream>>>(Ws, bs, ws_chunks);
    compose_final<<<1, 64, 0, stream>>>(ws_chunks, ws_aff);

    const int threads = 256;
    const int blocks  = (npairs + threads - 1) / threads;
    apply_affine<<<blocks, threads, 0, stream>>>(x, ws_aff, out, npairs);
}

// Round 2
// 171.466 us; speedup vs baseline: 1.5256x; 1.5256x over previous
//
#include <hip/hip_runtime.h>

#define NUM_LAYERS 1000
#define DIM 10
#define STRIDE 112           // floats per affine slot (10x11 = 110, padded to 112)
#define LPB 16               // layers per block in K1
#define NBLK 63              // ceil(1000/16)

// Affine stored col-major in a slot: slot[j*10 + r] = M[r][j] for j<10,
// slot[100 + r] = c[r] (i.e. column 10 of the 11x11 homogeneous matrix).
// Compose: dst = g(f(.)):  col_j(dst) = M_g * col_j(f)  (+ c_g when j==10).
// Lane j (0..10) owns column j. M_g reads are lane-uniform -> LDS broadcast;
// col_f reads hit distinct banks (10*j mod 32 distinct for j=0..10).
__device__ inline void compose_one(const float* __restrict__ src,
                                   float* __restrict__ dst,
                                   int c, int lane) {
    const float* F = src + (size_t)(2 * c) * STRIDE;
    const float* G = src + (size_t)(2 * c + 1) * STRIDE;
    float colf[DIM], o[DIM];
    #pragma unroll
    for (int r = 0; r < DIM; ++r) colf[r] = F[lane * DIM + r];
    #pragma unroll
    for (int r = 0; r < DIM; ++r) {
        float acc = (lane == DIM) ? G[100 + r] : 0.f;
        #pragma unroll
        for (int k = 0; k < DIM; ++k)
            acc += G[k * DIM + r] * colf[k];
        o[r] = acc;
    }
    float* D = dst + (size_t)c * STRIDE;
    #pragma unroll
    for (int r = 0; r < DIM; ++r) D[lane * DIM + r] = o[r];
}

// ---------------------------------------------------------------------------
// K1: block b composes layers [b*16, b*16+16) (identity-padded past 999) via
// a 4-level LDS tree: 16 -> 8 -> 4 -> 2 -> 1. One wave per compose.
// ---------------------------------------------------------------------------
__global__ __launch_bounds__(1024) void compose16(const float* __restrict__ Ws,
                                                  const float* __restrict__ bs,
                                                  float* __restrict__ wsout) {
    __shared__ float A[LPB * STRIDE];
    __shared__ float B[(LPB / 2) * STRIDE];
    const int tid = threadIdx.x;
    const int blk = blockIdx.x;

    // Coalesced load of 16 layers' W (row-major in global) -> col-major slots.
    for (int e = tid; e < LPB * 100; e += 1024) {
        int ll = e / 100, rem = e % 100;      // rem = r*10 + k
        int r = rem / 10, k = rem % 10;
        int l = blk * LPB + ll;
        float v = (l < NUM_LAYERS) ? Ws[(size_t)l * 100 + rem]
                                   : (r == k ? 1.f : 0.f);
        A[ll * STRIDE + k * DIM + r] = v;
    }
    for (int e = tid; e < LPB * DIM; e += 1024) {
        int ll = e / DIM, r = e % DIM;
        int l = blk * LPB + ll;
        float v = (l < NUM_LAYERS) ? bs[(size_t)l * DIM + r] : 0.f;
        A[ll * STRIDE + 100 + r] = v;
    }

    const int wave = tid >> 6, lane = tid & 63;
    const float* src = A;
    float* dst = B;
    for (int n = LPB / 2; n >= 1; n >>= 1) {   // n = 8,4,2,1
        __syncthreads();
        if (wave < n && lane <= DIM) compose_one(src, dst, wave, lane);
        const float* t = dst; dst = (float*)src; src = t;
    }
    // 4 levels (even count) -> final affine sits in A slot 0.
    __syncthreads();
    if (tid < 110) wsout[(size_t)blk * STRIDE + tid] = A[tid];
}

// ---------------------------------------------------------------------------
// K2: one block folds the 63 chunk affines (padded to 64 with identity) via a
// 6-level LDS tree: 64 -> 32 -> 16 -> 8 -> 4 -> 2 -> 1. Writes the final
// affine ROW-major for the apply kernel: aff[r*10+k] = M[r][k], aff[100+r]=c.
// ---------------------------------------------------------------------------
__global__ __launch_bounds__(1024) void compose_tree64(const float* __restrict__ wsin,
                                                       float* __restrict__ aff) {
    __shared__ float A[64 * STRIDE];
    __shared__ float B[32 * STRIDE];
    const int tid = threadIdx.x;

    for (int e = tid; e < 64 * STRIDE; e += 1024) {
        int chunk = e / STRIDE, pos = e % STRIDE;
        float v;
        if (pos >= 110)      v = 0.f;
        else if (chunk < NBLK) v = wsin[(size_t)chunk * STRIDE + pos];
        else v = (pos < 100 && (pos / 10 == pos % 10)) ? 1.f : 0.f;  // identity
        A[e] = v;
    }

    const int wave = tid >> 6, lane = tid & 63;
    const float* src = A;
    float* dst = B;
    for (int n = 32; n >= 1; n >>= 1) {        // n = 32,16,8,4,2,1
        __syncthreads();
        if (lane <= DIM)
            for (int c = wave; c < n; c += 16)
                compose_one(src, dst, c, lane);
        const float* t = dst; dst = (float*)src; src = t;
    }
    // 6 levels (even) -> final in A slot 0 (col-major). Transpose M on write.
    __syncthreads();
    if (tid < 110) {
        if (tid < 100) {
            int j = tid / DIM, r = tid % DIM;  // A[j*10+r] = M[r][j]
            aff[r * DIM + j] = A[tid];
        } else {
            aff[tid] = A[tid];                 // bias
        }
    }
}

// ---------------------------------------------------------------------------
// K3: out = M x + c. Two rows/thread -> 80 B = 5 x float4 coalesced in/out.
// Affine broadcast from LDS (uniform addresses -> no conflicts).
// ---------------------------------------------------------------------------
__global__ __launch_bounds__(256) void apply_affine(const float* __restrict__ x,
                                                    const float* __restrict__ aff,
                                                    float* __restrict__ out,
                                                    int npairs) {
    __shared__ float s[112];
    if (threadIdx.x < 112)
        s[threadIdx.x] = (threadIdx.x < 110) ? aff[threadIdx.x] : 0.f;
    __syncthreads();

    const int t = blockIdx.x * blockDim.x + threadIdx.x;
    if (t >= npairs) return;

    const float4* xin = (const float4*)x + (size_t)t * 5;
    float4 v0 = xin[0], v1 = xin[1], v2 = xin[2], v3 = xin[3], v4 = xin[4];
    float xv[20] = {v0.x, v0.y, v0.z, v0.w,  v1.x, v1.y, v1.z, v1.w,
                    v2.x, v2.y, v2.z, v2.w,  v3.x, v3.y, v3.z, v3.w,
                    v4.x, v4.y, v4.z, v4.w};
    float o[20];
    #pragma unroll
    for (int rr = 0; rr < 2; ++rr) {
        #pragma unroll
        for (int j = 0; j < DIM; ++j) {
            float acc = s[100 + j];
            #pragma unroll
            for (int k = 0; k < DIM; ++k)
                acc += s[j * DIM + k] * xv[rr * DIM + k];
            o[rr * DIM + j] = acc;
        }
    }

    float4* op = (float4*)out + (size_t)t * 5;
    op[0] = make_float4(o[0],  o[1],  o[2],  o[3]);
    op[1] = make_float4(o[4],  o[5],  o[6],  o[7]);
    op[2] = make_float4(o[8],  o[9],  o[10], o[11]);
    op[3] = make_float4(o[12], o[13], o[14], o[15]);
    op[4] = make_float4(o[16], o[17], o[18], o[19]);
}

extern "C" void kernel_launch(void* const* d_in, const int* in_sizes, int n_in,
                              void* d_out, int out_size, void* d_ws, size_t ws_size,
                              hipStream_t stream) {
    const float* x  = (const float*)d_in[0];   // [BATCH, 10]
    const float* Ws = (const float*)d_in[1];   // [1000, 10, 10]
    const float* bs = (const float*)d_in[2];   // [1000, 10]
    float* out = (float*)d_out;

    float* ws_chunks = (float*)d_ws;                      // NBLK * STRIDE floats
    float* ws_aff    = ws_chunks + NBLK * STRIDE;         // 110 floats

    const int batch  = in_sizes[0] / DIM;
    const int npairs = batch / 2;

    compose16<<<NBLK, 1024, 0, stream>>>(Ws, bs, ws_chunks);
    compose_tree64<<<1, 1024, 0, stream>>>(ws_chunks, ws_aff);

    const int threads = 256;
    const int blocks  = (npairs + threads - 1) / threads;
    apply_affine<<<blocks, threads, 0, stream>>>(x, ws_aff, out, npairs);
}